// Round 5
// baseline (342.737 us; speedup 1.0000x reference)
//
#include <hip/hip_runtime.h>
#include <stdint.h>

#define TT 4096      // tokens
#define DM 1024      // d_model
#define NE 16        // experts
#define DFF 512      // per-expert ffn
#define DFS 1024     // shared ffn
#define CAP 1024     // capacity

typedef unsigned short u16;
typedef __bf16 bf16x8 __attribute__((ext_vector_type(8)));
typedef float f32x4 __attribute__((ext_vector_type(4)));

typedef __attribute__((address_space(1))) void as1_void;
typedef __attribute__((address_space(3))) void as3_void;

__device__ __forceinline__ u16 f2bf(float f) {
  union { float f; uint32_t u; } v; v.f = f;
  uint32_t u = v.u;
  u += 0x7fffu + ((u >> 16) & 1u);   // RNE
  return (u16)(u >> 16);
}

__device__ __forceinline__ float bf2f(u16 b) {
  union { uint32_t u; float f; } v; v.u = ((uint32_t)b) << 16;
  return v.f;
}

__device__ __forceinline__ void gl2lds16(const void* g, void* l) {
  __builtin_amdgcn_global_load_lds(
      (as1_void*)(uintptr_t)g,
      (as3_void*)(uint32_t)(uintptr_t)l,
      16, 0, 0);
}

// ============ PREP: router (+hidden bf16 cast) and all weight transposes ============
// bid < 256: router block (16 tokens, 16 k-split threads each)
// bid >= 256: one 64x64 transpose tile. tb = bid-256:
//   tb < 6144: expert weights, slice = tb>>7 (0-15 w1 | 16-31 w3 | 32-47 w2), ti = tb&127
//   else: shared weights, slice = (tb-6144)>>8 (ws1|ws3|ws2), ti = &255
__global__ __launch_bounds__(256) void k_prep(
    const float* __restrict__ x, const float* __restrict__ Wg,
    const float* __restrict__ w1, const float* __restrict__ w3,
    const float* __restrict__ w2, const float* __restrict__ ws1,
    const float* __restrict__ ws3, const float* __restrict__ ws2,
    u16* __restrict__ hbf,
    u16* __restrict__ w1t, u16* __restrict__ w3t, u16* __restrict__ w2t,
    u16* __restrict__ ws1t, u16* __restrict__ ws3t, u16* __restrict__ ws2t,
    int* __restrict__ counts, int* __restrict__ tok_slot,
    int* __restrict__ tslot, float* __restrict__ tw) {
  __shared__ __align__(16) char smraw[18624];
  const int bid = blockIdx.x;
  const int tid = threadIdx.x;

  if (bid < 256) {
    // ---------------- router ----------------
    float (*red)[16][17] = (float(*)[16][17])smraw;           // [token][kpart][expert]
    float (*lg)[17] = (float(*)[17])(smraw + 17408);          // [token][expert]
    int tl = tid >> 4, kp = tid & 15;
    int t = bid * 16 + tl;
    const float* xr = x + (size_t)t * DM + kp * 64;
    u16* hr = hbf + (size_t)t * DM + kp * 64;
    float acc[16];
#pragma unroll
    for (int e = 0; e < 16; ++e) acc[e] = 0.f;
#pragma unroll 4
    for (int i = 0; i < 16; ++i) {
      float4 xv = *(const float4*)(xr + i * 4);
      ushort4 o;
      o.x = f2bf(xv.x); o.y = f2bf(xv.y); o.z = f2bf(xv.z); o.w = f2bf(xv.w);
      *(ushort4*)(hr + i * 4) = o;
      const float* wgr = Wg + (size_t)(kp * 64 + i * 4) * NE;
#pragma unroll
      for (int q = 0; q < 4; ++q) {
        float xq = (q == 0) ? xv.x : (q == 1) ? xv.y : (q == 2) ? xv.z : xv.w;
        float4 a = *(const float4*)(wgr + q * NE);
        float4 b = *(const float4*)(wgr + q * NE + 4);
        float4 c = *(const float4*)(wgr + q * NE + 8);
        float4 d = *(const float4*)(wgr + q * NE + 12);
        acc[0] += xq * a.x;  acc[1] += xq * a.y;  acc[2] += xq * a.z;  acc[3] += xq * a.w;
        acc[4] += xq * b.x;  acc[5] += xq * b.y;  acc[6] += xq * b.z;  acc[7] += xq * b.w;
        acc[8] += xq * c.x;  acc[9] += xq * c.y;  acc[10] += xq * c.z; acc[11] += xq * c.w;
        acc[12] += xq * d.x; acc[13] += xq * d.y; acc[14] += xq * d.z; acc[15] += xq * d.w;
      }
    }
#pragma unroll
    for (int e = 0; e < 16; ++e) red[tl][kp][e] = acc[e];
    __syncthreads();
    float logit = 0.f;
#pragma unroll
    for (int p = 0; p < 16; ++p) logit += red[tl][p][kp];
    lg[tl][kp] = logit;
    __syncthreads();
    if (kp == 0) {
      float b0 = -1e30f; int i0 = 0;
#pragma unroll
      for (int i = 0; i < NE; ++i) { float v = lg[tl][i]; if (v > b0) { b0 = v; i0 = i; } }
      float b1 = -1e30f; int i1 = 0;
#pragma unroll
      for (int i = 0; i < NE; ++i) { if (i == i0) continue; float v = lg[tl][i]; if (v > b1) { b1 = v; i1 = i; } }
      float ex = __expf(b1 - b0);
      float w0 = 1.f / (1.f + ex);
      float w1v = 1.f - w0;
      int p0 = atomicAdd(&counts[i0], 1);
      int s0 = -1;
      if (p0 < CAP) { s0 = i0 * CAP + p0; tok_slot[s0] = t; }
      tslot[2 * t] = s0; tw[2 * t] = w0;
      int p1 = atomicAdd(&counts[i1], 1);
      int s1 = -1;
      if (p1 < CAP) { s1 = i1 * CAP + p1; tok_slot[s1] = t; }
      tslot[2 * t + 1] = s1; tw[2 * t + 1] = w1v;
    }
    return;
  }

  // ------- transpose-convert fp32 [R,C] -> bf16 [C,R], rotation-swizzled LDS -------
  // element (r,c) lives at word  r*64 + ((c+r)&63)  -> both phases conflict-free
  int tb = bid - 256;
  const float* ip; u16* op; int R, C, rt, ct;
  if (tb < 6144) {
    int slice = tb >> 7, ti = tb & 127;
    if (slice < 16)      { ip = w1 + (size_t)slice * DM * DFF; op = w1t + (size_t)slice * DM * DFF; R = DM;  C = DFF; rt = ti >> 3; ct = ti & 7; }
    else if (slice < 32) { int e = slice - 16; ip = w3 + (size_t)e * DM * DFF; op = w3t + (size_t)e * DM * DFF; R = DM;  C = DFF; rt = ti >> 3; ct = ti & 7; }
    else                 { int e = slice - 32; ip = w2 + (size_t)e * DFF * DM; op = w2t + (size_t)e * DFF * DM; R = DFF; C = DM;  rt = ti >> 4; ct = ti & 15; }
  } else {
    int tb2 = tb - 6144; int slice = tb2 >> 8, ti = tb2 & 255;
    if (slice == 0)      { ip = ws1; op = ws1t; }
    else if (slice == 1) { ip = ws3; op = ws3t; }
    else                 { ip = ws2; op = ws2t; }
    R = 1024; C = 1024; rt = ti >> 4; ct = ti & 15;
  }
  int r0 = rt * 64, c0 = ct * 64;

  float* tile = (float*)smraw;
  int tx = tid & 15, ty = tid >> 4;
#pragma unroll
  for (int j = 0; j < 4; ++j) {
    int r = ty + 16 * j;
    float4 v = *(const float4*)&ip[(size_t)(r0 + r) * C + c0 + tx * 4];
    int base = r * 64;
    int cc = tx * 4;
    tile[base + ((cc + 0 + r) & 63)] = v.x;
    tile[base + ((cc + 1 + r) & 63)] = v.y;
    tile[base + ((cc + 2 + r) & 63)] = v.z;
    tile[base + ((cc + 3 + r) & 63)] = v.w;
  }
  __syncthreads();
#pragma unroll
  for (int j = 0; j < 4; ++j) {
    int c = ty + 16 * j;
    int rr = tx * 4;
    ushort4 o;
    o.x = f2bf(tile[(rr + 0) * 64 + ((c + rr + 0) & 63)]);
    o.y = f2bf(tile[(rr + 1) * 64 + ((c + rr + 1) & 63)]);
    o.z = f2bf(tile[(rr + 2) * 64 + ((c + rr + 2) & 63)]);
    o.w = f2bf(tile[(rr + 3) * 64 + ((c + rr + 3) & 63)]);
    *(ushort4*)&op[(size_t)(c0 + c) * R + r0 + rr] = o;
  }
}

// LDS tile rows are 64 u16 = 128B = 8 chunks of 16B; chunk c of row r in slot c^(r&7).
#define FRAG(BUF, ROW, CC)                                                       \
  (*(const bf16x8*)&BUF[(ROW) * 64 + ((((CC) * 4 + lq) ^ ((ROW) & 7)) << 3)])

// ============ UP: 128x64 tile, 2 waves, BK=64, dual-B, silu(a1)*a3 -> bf16 ============
// bid < 512: shared (A=hbf, B=ws1t/ws3t, C=hs, N=DFS)
// bid >= 512: routed (A=gather(hbf), B=w1t/w3t[e], C=hexp[e], N=DFF)
__global__ __launch_bounds__(128) void k_up(
    const u16* __restrict__ hbf,
    const u16* __restrict__ ws1t, const u16* __restrict__ ws3t,
    const u16* __restrict__ w1t, const u16* __restrict__ w3t,
    u16* __restrict__ hs, u16* __restrict__ hexp,
    const int* __restrict__ counts, const int* __restrict__ tok_slot) {
  const int bid = blockIdx.x;
  const int tid = threadIdx.x;
  const u16* B1p; const u16* B3p; u16* Cp;
  int m0, n0, N;
  int e = -1, cnt = 0;
  if (bid < 512) {
    m0 = (bid >> 4) * 128; n0 = (bid & 15) * 64;
    B1p = ws1t; B3p = ws3t; Cp = hs; N = DFS;
  } else {
    int r = bid - 512;                  // 1024 routed: e * (8 m-tiles x 8 n-tiles)
    e = r >> 6; int q = r & 63;
    m0 = (q >> 3) * 128; n0 = (q & 7) * 64;
    cnt = counts[e]; if (cnt > CAP) cnt = CAP;
    if (m0 >= cnt) return;              // uniform exit before any barrier
    B1p = w1t + (size_t)e * (DFF * DM);
    B3p = w3t + (size_t)e * (DFF * DM);
    Cp = hexp + (size_t)e * (CAP * DFF);
    N = DFF;
  }

  __shared__ __align__(16) u16 As[128 * 64];
  __shared__ __align__(16) u16 Bs1[64 * 64];
  __shared__ __align__(16) u16 Bs3[64 * 64];

  uint32_t aoff[8], boff[4];
#pragma unroll
  for (int j = 0; j < 8; ++j) {
    int L = tid + 128 * j;
    int row = L >> 3;
    int c = (L & 7) ^ (row & 7);
    int gr;
    if (e >= 0) {
      int rr = m0 + row;
      gr = (rr < cnt) ? tok_slot[e * CAP + rr] : 0;
    } else {
      gr = m0 + row;
    }
    aoff[j] = (uint32_t)gr * DM + c * 8;
  }
#pragma unroll
  for (int j = 0; j < 4; ++j) {
    int L = tid + 128 * j;
    int row = L >> 3;
    int c = (L & 7) ^ (row & 7);
    boff[j] = (uint32_t)(n0 + row) * DM + c * 8;
  }

  const int lane = tid & 63;
  const int wv = tid >> 6;
  const int wr = wv * 64;
  const int lr = lane & 15;
  const int lq = lane >> 4;

  f32x4 acc1[4][4], acc3[4][4];
#pragma unroll
  for (int i = 0; i < 4; ++i)
#pragma unroll
    for (int j = 0; j < 4; ++j) {
      acc1[i][j] = (f32x4){0.f, 0.f, 0.f, 0.f};
      acc3[i][j] = (f32x4){0.f, 0.f, 0.f, 0.f};
    }

  for (int k0 = 0; k0 < DM; k0 += 64) {
    __syncthreads();
#pragma unroll
    for (int j = 0; j < 8; ++j) gl2lds16(hbf + aoff[j] + k0, &As[(size_t)(tid + 128 * j) * 8]);
#pragma unroll
    for (int j = 0; j < 4; ++j) gl2lds16(B1p + boff[j] + k0, &Bs1[(size_t)(tid + 128 * j) * 8]);
#pragma unroll
    for (int j = 0; j < 4; ++j) gl2lds16(B3p + boff[j] + k0, &Bs3[(size_t)(tid + 128 * j) * 8]);
    __syncthreads();
#pragma unroll
    for (int cc = 0; cc < 2; ++cc) {
      bf16x8 af[4], bf1[4], bf3[4];
#pragma unroll
      for (int i = 0; i < 4; ++i) af[i] = FRAG(As, wr + i * 16 + lr, cc);
#pragma unroll
      for (int j = 0; j < 4; ++j) {
        bf1[j] = FRAG(Bs1, j * 16 + lr, cc);
        bf3[j] = FRAG(Bs3, j * 16 + lr, cc);
      }
#pragma unroll
      for (int i = 0; i < 4; ++i)
#pragma unroll
        for (int j = 0; j < 4; ++j) {
          acc1[i][j] = __builtin_amdgcn_mfma_f32_16x16x32_bf16(af[i], bf1[j], acc1[i][j], 0, 0, 0);
          acc3[i][j] = __builtin_amdgcn_mfma_f32_16x16x32_bf16(af[i], bf3[j], acc3[i][j], 0, 0, 0);
        }
    }
  }

#pragma unroll
  for (int i = 0; i < 4; ++i)
#pragma unroll
    for (int r = 0; r < 4; ++r) {
      int row = m0 + wr + i * 16 + lq * 4 + r;
      u16* crow = Cp + (size_t)row * N;
#pragma unroll
      for (int j = 0; j < 4; ++j) {
        float v1 = acc1[i][j][r];
        float v3 = acc3[i][j][r];
        float h = (v1 / (1.f + __expf(-v1))) * v3;   // silu(v1)*v3
        crow[n0 + j * 16 + lr] = f2bf(h);
      }
    }
}

// ============ DOWN: 128x64 tile, 2 waves, BK=64, single-B, ALL PLAIN STORES ============
// bid < 512: shared (A=hs, B=ws2t, K=DFS) -> out fp32 (covers every element)
// bid >= 512: routed (A=hexp[e], B=w2t[e], K=DFF) -> ob bf16 per-slot rows
__global__ __launch_bounds__(128) void k_down(
    const u16* __restrict__ hs, const u16* __restrict__ ws2t,
    const u16* __restrict__ hexp, const u16* __restrict__ w2t,
    float* __restrict__ out, u16* __restrict__ ob,
    const int* __restrict__ counts) {
  const int bid = blockIdx.x;
  const int tid = threadIdx.x;
  const u16* Ap; const u16* Bp;
  int m0, n0, K, e = -1;
  if (bid < 512) {
    m0 = (bid >> 4) * 128; n0 = (bid & 15) * 64;
    Ap = hs; Bp = ws2t; K = DFS;
  } else {
    int r = bid - 512;                  // 2048 routed: e * (8 m-tiles x 16 n-tiles)
    e = r >> 7; int q = r & 127;
    m0 = (q >> 4) * 128; n0 = (q & 15) * 64;
    int cnt = counts[e]; if (cnt > CAP) cnt = CAP;
    if (m0 >= cnt) return;
    Ap = hexp + (size_t)e * (CAP * DFF);
    Bp = w2t + (size_t)e * (DM * DFF);
    K = DFF;
  }

  __shared__ __align__(16) u16 As[128 * 64];
  __shared__ __align__(16) u16 Bs[64 * 64];

  uint32_t aoff[8], boff[4];
#pragma unroll
  for (int j = 0; j < 8; ++j) {
    int L = tid + 128 * j;
    int row = L >> 3;
    int c = (L & 7) ^ (row & 7);
    aoff[j] = (uint32_t)(m0 + row) * K + c * 8;
  }
#pragma unroll
  for (int j = 0; j < 4; ++j) {
    int L = tid + 128 * j;
    int row = L >> 3;
    int c = (L & 7) ^ (row & 7);
    boff[j] = (uint32_t)(n0 + row) * K + c * 8;
  }

  const int lane = tid & 63;
  const int wv = tid >> 6;
  const int wr = wv * 64;
  const int lr = lane & 15;
  const int lq = lane >> 4;

  f32x4 acc[4][4];
#pragma unroll
  for (int i = 0; i < 4; ++i)
#pragma unroll
    for (int j = 0; j < 4; ++j) acc[i][j] = (f32x4){0.f, 0.f, 0.f, 0.f};

  for (int k0 = 0; k0 < K; k0 += 64) {
    __syncthreads();
#pragma unroll
    for (int j = 0; j < 8; ++j) gl2lds16(Ap + aoff[j] + k0, &As[(size_t)(tid + 128 * j) * 8]);
#pragma unroll
    for (int j = 0; j < 4; ++j) gl2lds16(Bp + boff[j] + k0, &Bs[(size_t)(tid + 128 * j) * 8]);
    __syncthreads();
#pragma unroll
    for (int cc = 0; cc < 2; ++cc) {
      bf16x8 af[4], bfr[4];
#pragma unroll
      for (int i = 0; i < 4; ++i) af[i] = FRAG(As, wr + i * 16 + lr, cc);
#pragma unroll
      for (int j = 0; j < 4; ++j) bfr[j] = FRAG(Bs, j * 16 + lr, cc);
#pragma unroll
      for (int i = 0; i < 4; ++i)
#pragma unroll
        for (int j = 0; j < 4; ++j)
          acc[i][j] = __builtin_amdgcn_mfma_f32_16x16x32_bf16(af[i], bfr[j], acc[i][j], 0, 0, 0);
    }
  }

  if (e < 0) {
#pragma unroll
    for (int i = 0; i < 4; ++i)
#pragma unroll
      for (int r = 0; r < 4; ++r) {
        int row = m0 + wr + i * 16 + lq * 4 + r;
        float* orow = out + (size_t)row * DM;
#pragma unroll
        for (int j = 0; j < 4; ++j)
          orow[n0 + j * 16 + lr] = acc[i][j][r];
      }
  } else {
    u16* obase = ob + (size_t)e * CAP * DM;
#pragma unroll
    for (int i = 0; i < 4; ++i)
#pragma unroll
      for (int r = 0; r < 4; ++r) {
        int row = m0 + wr + i * 16 + lq * 4 + r;
        u16* orow = obase + (size_t)row * DM;
#pragma unroll
        for (int j = 0; j < 4; ++j)
          orow[n0 + j * 16 + lr] = f2bf(acc[i][j][r]);
      }
  }
}

// ============ COMBINE: out[t] += w0*ob[s0] + w1*ob[s1] ============
__global__ __launch_bounds__(256) void k_combine(
    float* __restrict__ out, const u16* __restrict__ ob,
    const int* __restrict__ tslot, const float* __restrict__ tw) {
  int t = blockIdx.x;
  int c = threadIdx.x * 4;
  int s0 = tslot[2 * t], s1 = tslot[2 * t + 1];
  float w0 = tw[2 * t], w1 = tw[2 * t + 1];
  float4 v = *(float4*)&out[(size_t)t * DM + c];
  if (s0 >= 0) {
    ushort4 o = *(const ushort4*)&ob[(size_t)s0 * DM + c];
    v.x += w0 * bf2f(o.x); v.y += w0 * bf2f(o.y);
    v.z += w0 * bf2f(o.z); v.w += w0 * bf2f(o.w);
  }
  if (s1 >= 0) {
    ushort4 o = *(const ushort4*)&ob[(size_t)s1 * DM + c];
    v.x += w1 * bf2f(o.x); v.y += w1 * bf2f(o.y);
    v.z += w1 * bf2f(o.z); v.w += w1 * bf2f(o.w);
  }
  *(float4*)&out[(size_t)t * DM + c] = v;
}

// ---------------- host ----------------
extern "C" void kernel_launch(void* const* d_in, const int* in_sizes, int n_in,
                              void* d_out, int out_size, void* d_ws, size_t ws_size,
                              hipStream_t stream) {
  (void)in_sizes; (void)n_in; (void)out_size; (void)ws_size;
  const float* x   = (const float*)d_in[0];
  const float* Wg  = (const float*)d_in[1];
  const float* w1  = (const float*)d_in[2];
  const float* w3  = (const float*)d_in[3];
  const float* w2  = (const float*)d_in[4];
  const float* ws1 = (const float*)d_in[5];
  const float* ws3 = (const float*)d_in[6];
  const float* ws2 = (const float*)d_in[7];
  float* out = (float*)d_out;
  char* ws = (char*)d_ws;

  u16* hbf   = (u16*)(ws + 0);          // 8 MB   [TT,DM] bf16          (dead after k_up)
  u16* w1t   = (u16*)(ws + 8388608);    // 16 MB  [E][DFF][DM]          (dead after k_up)
  u16* w3t   = (u16*)(ws + 25165824);   // 16 MB                        (dead after k_up)
  u16* w2t   = (u16*)(ws + 41943040);   // 16 MB  [E][DM][DFF]
  u16* ws1t  = (u16*)(ws + 58720256);   // 2 MB   [DFS][DM]
  u16* ws3t  = (u16*)(ws + 60817408);   // 2 MB
  u16* ws2t  = (u16*)(ws + 62914560);   // 2 MB   [DM][DFS]
  u16* hs    = (u16*)(ws + 65011712);   // 8 MB   [TT,DFS] bf16
  u16* hexp  = (u16*)(ws + 73400320);   // 16 MB  [E][CAP][DFF] bf16
  int* counts    = (int*)(ws + 90177536);
  int* tok_slot  = (int*)(ws + 90177792);   // 64 KB
  int* tslot     = (int*)(ws + 90243328);   // 32 KB [TT*2]
  float* tw      = (float*)(ws + 90276096); // 32 KB [TT*2]
  u16* ob    = (u16*)(ws + 0);          // 33.5 MB [E*CAP, DM] bf16 — aliases hbf/w1t/w3t
                                        // (written only in k_down, after those are dead)

  hipMemsetAsync(counts, 0, NE * sizeof(int), stream);

  // prep: 256 router blocks + 6912 transpose tiles (48*128 expert + 3*256 shared)
  k_prep<<<dim3(256 + 6912), dim3(256), 0, stream>>>(
      x, Wg, w1, w3, w2, ws1, ws3, ws2,
      hbf, w1t, w3t, w2t, ws1t, ws3t, ws2t,
      counts, tok_slot, tslot, tw);

  // up: 512 shared tiles (32m x 16n) + 1024 routed tiles (16e x 8m x 8n)
  k_up<<<dim3(512 + NE * 64), dim3(128), 0, stream>>>(
      hbf, ws1t, ws3t, w1t, w3t, hs, hexp, counts, tok_slot);

  // down: 512 shared tiles -> out (plain fp32) + 2048 routed tiles -> ob (plain bf16)
  k_down<<<dim3(512 + NE * 128), dim3(128), 0, stream>>>(
      hs, ws2t, hexp, w2t, out, ob, counts);

  // combine: out[t] += w0*ob[s0] + w1*ob[s1]
  k_combine<<<dim3(TT), dim3(256), 0, stream>>>(out, ob, tslot, tw);
}